// Round 12
// baseline (181.326 us; speedup 1.0000x reference)
//
#include <hip/hip_runtime.h>
#include <hip/hip_bf16.h>
#include <stdint.h>

// MambaBlock: B=2, T=1024, D_MODEL=1024, D_INNER=2048, GROUPS=16, D_STATE=16
#define ROWS 2048      // B*T
#define DM   1024
#define DI   2048
#define PPAD 640       // 528 param rows padded to 5*128

typedef __bf16 bf16_t;
typedef __attribute__((ext_vector_type(8))) __bf16 bf16x8;
typedef __attribute__((ext_vector_type(4))) __bf16 bf16x4;
typedef __attribute__((ext_vector_type(4))) float f32x4;
typedef __attribute__((address_space(1))) void gvoid_t;
typedef __attribute__((address_space(3))) void lvoid_t;

// ---------------- prep0: W_in + W_param -> bf16, z = rmsnorm(x,g1) ----------
__global__ __launch_bounds__(256) void prep0(const float* __restrict__ W_in,
                                             const float* __restrict__ W_param,
                                             bf16_t* o_in, bf16_t* o_par,
                                             const float* __restrict__ x,
                                             const float* __restrict__ g1,
                                             bf16_t* __restrict__ zb) {
  int tid = threadIdx.x;
  if (blockIdx.x >= 5376) {  // rmsnorm
    int row = blockIdx.x - 5376;
    const float4 v = *(const float4*)(x + (int64_t)row * DM + tid * 4);
    float ss = v.x * v.x + v.y * v.y + v.z * v.z + v.w * v.w;
#pragma unroll
    for (int o = 32; o; o >>= 1) ss += __shfl_xor(ss, o, 64);
    __shared__ float red[4];
    if ((tid & 63) == 0) red[tid >> 6] = ss;
    __syncthreads();
    float tot = red[0] + red[1] + red[2] + red[3];
    float sc = rsqrtf(tot * (1.0f / DM) + 1e-6f);
    const float4 gv = *(const float4*)(g1 + tid * 4);
    bf16_t* o = zb + (int64_t)row * DM + tid * 4;
    o[0] = (bf16_t)(v.x * sc * gv.x);
    o[1] = (bf16_t)(v.y * sc * gv.y);
    o[2] = (bf16_t)(v.z * sc * gv.z);
    o[3] = (bf16_t)(v.w * sc * gv.w);
    return;
  }
  if (blockIdx.x >= 4096) {  // W_param, zero-padded 528 -> 640 rows
    int64_t e = (((int64_t)(blockIdx.x - 4096)) * 256 + tid) * 4;
    int row = (int)(e >> 11), col = (int)(e & 2047);
    float4 v = make_float4(0.f, 0.f, 0.f, 0.f);
    if (row < 528) v = *(const float4*)(W_param + (int64_t)row * 2048 + col);
    bf16_t* o = o_par + e;
    o[0] = (bf16_t)v.x; o[1] = (bf16_t)v.y; o[2] = (bf16_t)v.z; o[3] = (bf16_t)v.w;
    return;
  }
  int64_t e = ((int64_t)blockIdx.x * 256 + tid) * 4;
  float4 v = *(const float4*)(W_in + e);
  bf16_t* o = o_in + e;
  o[0] = (bf16_t)v.x; o[1] = (bf16_t)v.y; o[2] = (bf16_t)v.z; o[3] = (bf16_t)v.w;
}

// ---------------- conversion of W_out/W_f1/W_f2 (10240 blocks) --------------
__device__ __forceinline__ void conv3(int64_t c, int tid,
                                      const float* __restrict__ W_out,
                                      const float* __restrict__ W_f1,
                                      const float* __restrict__ W_f2,
                                      bf16_t* o_out, bf16_t* o_f1, bf16_t* o_f2) {
  const float* src; bf16_t* dst; int64_t e;
  if (c < 2048) { e = (c * 256 + tid) * 4; src = W_out; dst = o_out; }
  else if (c < 6144) { e = ((c - 2048) * 256 + tid) * 4; src = W_f1; dst = o_f1; }
  else { e = ((c - 6144) * 256 + tid) * 4; src = W_f2; dst = o_f2; }
  float4 v = *(const float4*)(src + e);
  bf16_t* o = dst + e;
  o[0] = (bf16_t)v.x; o[1] = (bf16_t)v.y; o[2] = (bf16_t)v.z; o[3] = (bf16_t)v.w;
}

__global__ __launch_bounds__(256) void cvt3_k(const float* __restrict__ W_out,
                                              const float* __restrict__ W_f1,
                                              const float* __restrict__ W_f2,
                                              bf16_t* o_out, bf16_t* o_f1,
                                              bf16_t* o_f2) {
  conv3(blockIdx.x, threadIdx.x, W_out, W_f1, W_f2, o_out, o_f1, o_f2);
}

// ---------------- rmsnorm (fallback) ----------------
__global__ __launch_bounds__(256) void rmsnorm_k(const float* __restrict__ x,
                                                 const float* __restrict__ g,
                                                 bf16_t* __restrict__ out) {
  int row = blockIdx.x;
  int tid = threadIdx.x;
  const float4 v = *(const float4*)(x + (int64_t)row * DM + tid * 4);
  float ss = v.x * v.x + v.y * v.y + v.z * v.z + v.w * v.w;
#pragma unroll
  for (int o = 32; o; o >>= 1) ss += __shfl_xor(ss, o, 64);
  __shared__ float red[4];
  if ((tid & 63) == 0) red[tid >> 6] = ss;
  __syncthreads();
  float tot = red[0] + red[1] + red[2] + red[3];
  float sc = rsqrtf(tot * (1.0f / DM) + 1e-6f);
  const float4 gv = *(const float4*)(g + tid * 4);
  bf16_t* o = out + (int64_t)row * DM + tid * 4;
  o[0] = (bf16_t)(v.x * sc * gv.x);
  o[1] = (bf16_t)(v.y * sc * gv.y);
  o[2] = (bf16_t)(v.z * sc * gv.z);
  o[3] = (bf16_t)(v.w * sc * gv.w);
}

// ---------------- silu + fp32 -> bf16 (fallback) ----------------
__global__ __launch_bounds__(256) void silu_cvt(const float* __restrict__ in,
                                                bf16_t* __restrict__ out,
                                                int in_stride, int ncols) {
  int64_t e = ((int64_t)blockIdx.x * 256 + threadIdx.x) * 4;
  int row = (int)(e / ncols);
  int col = (int)(e % ncols);
  const float4 v = *(const float4*)(in + (int64_t)row * in_stride + col);
  bf16_t* o = out + e;
  o[0] = (bf16_t)(v.x / (1.f + expf(-v.x)));
  o[1] = (bf16_t)(v.y / (1.f + expf(-v.y)));
  o[2] = (bf16_t)(v.z / (1.f + expf(-v.z)));
  o[3] = (bf16_t)(v.w / (1.f + expf(-v.w)));
}

// ---------------- standalone ssm_prep (fallback only) ----------------------
__global__ __launch_bounds__(256) void ssm_prep(const float* __restrict__ params,
                                                const float* __restrict__ A_log,
                                                float* __restrict__ ssmp) {
  int gid = blockIdx.x * 256 + threadIdx.x;  // 32 * 1024
  int bg = gid >> 10, t = gid & 1023;
  int b = bg >> 4, g = bg & 15;
  const float* pr = params + (int64_t)(b * 1024 + t) * PPAD + g * 33;
  float raw = pr[0];
  float delta = raw > 0.f ? raw + log1pf(expf(-raw)) : log1pf(expf(raw));
  float* o = ssmp + (int64_t)gid * 48;
#pragma unroll
  for (int s = 0; s < 16; ++s) {
    float A = -expf(A_log[s]);
    float dA = delta * A;
    dA = fminf(10.f, fmaxf(-10.f, dA));
    float e = expf(dA);
    float frac = (fabsf(dA) < 1e-4f) ? delta : (e - 1.f) / (A + 1e-12f);
    o[s] = dA;
    o[16 + s] = frac * pr[1 + s];
    o[32 + s] = pr[17 + s];
  }
}

// ---------------- split-K reduce (bf16 partials) + residual + rmsnorm -------
__global__ __launch_bounds__(256) void reduce_rms(const bf16_t* __restrict__ P,
                                                  const float* __restrict__ x,
                                                  const float* __restrict__ g,
                                                  bf16_t* __restrict__ xmid,
                                                  bf16_t* __restrict__ zb) {
  int row = blockIdx.x;
  int tid = threadIdx.x;
  int64_t base = (int64_t)row * DM + tid * 4;
  float4 v = *(const float4*)(x + base);
#pragma unroll
  for (int p = 0; p < 4; ++p) {
    bf16x4 pv = *(const bf16x4*)(P + (int64_t)p * ROWS * DM + base);
    v.x += (float)pv[0]; v.y += (float)pv[1]; v.z += (float)pv[2]; v.w += (float)pv[3];
  }
  bf16x4 xm;
  xm[0] = (bf16_t)v.x; xm[1] = (bf16_t)v.y; xm[2] = (bf16_t)v.z; xm[3] = (bf16_t)v.w;
  *(bf16x4*)(xmid + base) = xm;
  float ss = v.x * v.x + v.y * v.y + v.z * v.z + v.w * v.w;
#pragma unroll
  for (int o = 32; o; o >>= 1) ss += __shfl_xor(ss, o, 64);
  __shared__ float red[4];
  if ((tid & 63) == 0) red[tid >> 6] = ss;
  __syncthreads();
  float tot = red[0] + red[1] + red[2] + red[3];
  float sc = rsqrtf(tot * (1.0f / DM) + 1e-6f);
  const float4 gv = *(const float4*)(g + tid * 4);
  bf16_t* o = zb + base;
  o[0] = (bf16_t)(v.x * sc * gv.x);
  o[1] = (bf16_t)(v.y * sc * gv.y);
  o[2] = (bf16_t)(v.z * sc * gv.z);
  o[3] = (bf16_t)(v.w * sc * gv.w);
}

__global__ __launch_bounds__(256) void reduce_bias(const bf16_t* __restrict__ P,
                                                   const bf16_t* __restrict__ res,
                                                   const float* __restrict__ bias,
                                                   float* __restrict__ out) {
  int64_t e = ((int64_t)blockIdx.x * 256 + threadIdx.x) * 4;
  int col = (int)(e % DM);
  bf16x4 rv = *(const bf16x4*)(res + e);
  const float4 bv = *(const float4*)(bias + col);
  float4 v = make_float4((float)rv[0] + bv.x, (float)rv[1] + bv.y,
                         (float)rv[2] + bv.z, (float)rv[3] + bv.w);
#pragma unroll
  for (int p = 0; p < 4; ++p) {
    bf16x4 pv = *(const bf16x4*)(P + (int64_t)p * ROWS * DM + e);
    v.x += (float)pv[0]; v.y += (float)pv[1]; v.z += (float)pv[2]; v.w += (float)pv[3];
  }
  *(float4*)(out + e) = v;
}

// inline prep: compute 64 rows of coefficients into cf[64*48] from bf16
// split-K partials (4 parts). cf row t: { dA[16], frac*b[16], c[16] }.
__device__ __forceinline__ void prep_rows(const bf16_t* __restrict__ pb,
                                          const float* __restrict__ A_log,
                                          float* cf, int b, int g, int t0,
                                          int tid) {
  if (tid >= 64) return;
  int t = tid;
  int64_t row = (int64_t)(b * 1024) + t0 + t;
  float acc[33];
#pragma unroll
  for (int i = 0; i < 33; ++i) acc[i] = 0.f;
#pragma unroll
  for (int p = 0; p < 4; ++p) {
    const bf16_t* pr = pb + (int64_t)p * ROWS * PPAD + row * PPAD + g * 33;
#pragma unroll
    for (int i = 0; i < 33; ++i) acc[i] += (float)pr[i];
  }
  float raw = acc[0];
  float delta = raw > 0.f ? raw + log1pf(expf(-raw)) : log1pf(expf(raw));
  float* o = cf + t * 48;
#pragma unroll
  for (int s = 0; s < 16; ++s) {
    float A = -expf(A_log[s]);
    float dA = delta * A;
    dA = fminf(10.f, fmaxf(-10.f, dA));
    float e = expf(dA);
    float frac = (fabsf(dA) < 1e-4f) ? delta : (e - 1.f) / (A + 1e-12f);
    o[s] = dA;
    o[16 + s] = frac * acc[1 + s];
    o[32 + s] = acc[17 + s];
  }
}

// Ut layout: element (ch, t) at byte ch*128 + ((t*2) ^ ((ch&7)<<4))

// ---------------- Phase A: per-chunk boundary operator (MFMA) ---------------
// grid 480: chunks 0..14 only (chunk 15's S/Etot are never consumed)
template <int PREP>
__global__ __launch_bounds__(256) void ssm_chunk(const float* __restrict__ ssmp,
                                                 const bf16_t* __restrict__ pb,
                                                 const float* __restrict__ A_log,
                                                 const bf16_t* __restrict__ u,
                                                 float* __restrict__ S,
                                                 float* __restrict__ Etot) {
  __shared__ __align__(16) float cf[64 * 48];
  __shared__ __align__(16) float Lb[64 * 16];
  __shared__ __align__(16) bf16_t wl[16 * 64];
  __shared__ __align__(16) bf16_t Ut[128 * 64];
  int bg = blockIdx.x / 15, c = blockIdx.x % 15;
  int bgc = bg * 16 + c;
  int b = bg >> 4, g = bg & 15;
  int t0 = c * 64;
  int tid = threadIdx.x;
  {
    int lt = tid >> 4;
    int c8 = (tid & 15) * 8;
#pragma unroll
    for (int p = 0; p < 4; ++p) {
      int t = p * 16 + lt;
      bf16x8 v = *(const bf16x8*)(u + ((int64_t)(b * 1024) + t0 + t) * 2048 + g * 128 + c8);
#pragma unroll
      for (int j = 0; j < 8; ++j)
        Ut[(c8 + j) * 64 + (((t >> 3) ^ j) << 3) + (t & 7)] = v[j];
    }
  }
  if (PREP) {
    prep_rows(pb, A_log, cf, b, g, t0, tid);
  } else {
    const float4* src = (const float4*)(ssmp + ((int64_t)bg * 1024 + t0) * 48);
    float4* dst = (float4*)cf;
#pragma unroll
    for (int i = 0; i < 3; ++i) dst[i * 256 + tid] = src[i * 256 + tid];
  }
  __syncthreads();
  if (tid < 16) {
    float l = 0.f;
    for (int t = 0; t < 64; ++t) { l += cf[t * 48 + tid]; Lb[t * 16 + tid] = l; }
  }
  __syncthreads();
  {
    int s = tid >> 4, tb4 = (tid & 15) * 4;
    float lend = Lb[63 * 16 + s];
    bf16x4 wv;
#pragma unroll
    for (int j = 0; j < 4; ++j) {
      int t = tb4 + j;
      wv[j] = (bf16_t)(__expf(lend - Lb[t * 16 + s]) * cf[t * 48 + 16 + s]);
    }
    unsigned byo = (unsigned)(s * 128 + tb4 * 2) ^ ((unsigned)(s & 7) << 4);
    *(bf16x4*)((char*)wl + byo) = wv;
    if (tid < 16) Etot[(int64_t)bgc * 16 + tid] = __expf(Lb[63 * 16 + tid]);
  }
  __syncthreads();
  {
    int lane = tid & 63, wave = tid >> 6;
    int fr = lane & 15, kq = lane >> 4;
    f32x4 acc2[2] = {};
#pragma unroll
    for (int kk = 0; kk < 2; ++kk) {
      int kb = kk * 4 + kq;
      bf16x8 af = *(const bf16x8*)((const char*)wl +
                    ((unsigned)(fr * 128 + kb * 16) ^ ((unsigned)(fr & 7) << 4)));
#pragma unroll
      for (int q = 0; q < 2; ++q) {
        int ch = (wave * 2 + q) * 16 + fr;
        bf16x8 bfr = *(const bf16x8*)((const char*)Ut +
                       ((unsigned)(ch * 128 + kb * 16) ^ ((unsigned)(ch & 7) << 4)));
        acc2[q] = __builtin_amdgcn_mfma_f32_16x16x32_bf16(af, bfr, acc2[q], 0, 0, 0);
      }
    }
    float* Sp = S + (int64_t)bgc * 2048;
#pragma unroll
    for (int q = 0; q < 2; ++q) {
      int ch = (wave * 2 + q) * 16 + fr;
#pragma unroll
      for (int j = 0; j < 4; ++j) Sp[(kq * 4 + j) * 128 + ch] = acc2[q][j];
    }
  }
}

// ---------------- Phase C: combine (inline) + y = tril(K)@U + ce@H + gate ---
template <int PREP, int GM>
__global__ __launch_bounds__(256) void ssm_out(const float* __restrict__ ssmp,
                                               const bf16_t* __restrict__ pb,
                                               const float* __restrict__ A_log,
                                               const bf16_t* __restrict__ u,
                                               const float* __restrict__ S,
                                               const float* __restrict__ Etot,
                                               const float* __restrict__ gate_f,
                                               const bf16_t* __restrict__ gate_b,
                                               int gstride,
                                               bf16_t* __restrict__ yout) {
  __shared__ __align__(16) float cf[64 * 48];
  __shared__ __align__(16) float Lb[64 * 16];
  __shared__ __align__(16) bf16_t Km[64 * 64];
  __shared__ __align__(16) bf16_t Ut[128 * 64];
  __shared__ __align__(16) bf16_t Hb[128 * 32];
  int bgc = blockIdx.x;
  int bg = bgc >> 4, c = bgc & 15;
  int b = bg >> 4, g = bg & 15;
  int t0 = c * 64;
  int tid = threadIdx.x;
  int lane = tid & 63, wave = tid >> 6;
  {
    int lt = tid >> 4;
    int c8 = (tid & 15) * 8;
#pragma unroll
    for (int p = 0; p < 4; ++p) {
      int t = p * 16 + lt;
      bf16x8 v = *(const bf16x8*)(u + ((int64_t)(b * 1024) + t0 + t) * 2048 + g * 128 + c8);
#pragma unroll
      for (int j = 0; j < 8; ++j)
        Ut[(c8 + j) * 64 + (((t >> 3) ^ j) << 3) + (t & 7)] = v[j];
    }
  }
  // inline sequential combine over preceding chunks -> Hb[ch][s] (bf16)
  {
    int ch = tid & 127, s0 = (tid >> 7) * 8;
    const float* Sp = S + (int64_t)(bg * 16) * 2048;
    const float* Ep = Etot + (int64_t)(bg * 16) * 16;
    float h[8];
#pragma unroll
    for (int j = 0; j < 8; ++j) h[j] = 0.f;
    for (int cc = 0; cc < c; ++cc) {
#pragma unroll
      for (int j = 0; j < 8; ++j)
        h[j] = Ep[cc * 16 + s0 + j] * h[j] +
               Sp[(int64_t)cc * 2048 + (s0 + j) * 128 + ch];
    }
#pragma unroll
    for (int j = 0; j < 8; ++j) {
      Hb[ch * 32 + s0 + j] = (bf16_t)h[j];
      Hb[ch * 32 + 16 + s0 + j] = (bf16_t)0.f;
    }
  }
  if (PREP) {
    prep_rows(pb, A_log, cf, b, g, t0, tid);
  } else {
    const float4* src = (const float4*)(ssmp + ((int64_t)bg * 1024 + t0) * 48);
    float4* dst = (float4*)cf;
#pragma unroll
    for (int i = 0; i < 3; ++i) dst[i * 256 + tid] = src[i * 256 + tid];
  }
  __syncthreads();
  if (tid < 16) {
    float l = 0.f;
    for (int t = 0; t < 64; ++t) { l += cf[t * 48 + tid]; Lb[t * 16 + tid] = l; }
  }
  __syncthreads();
  {
    int t = tid >> 2, tp0 = (tid & 3) * 16;
    float4 cv[4], lv[4];
#pragma unroll
    for (int i = 0; i < 4; ++i) {
      cv[i] = *(const float4*)&cf[t * 48 + 32 + i * 4];
      lv[i] = *(const float4*)&Lb[t * 16 + i * 4];
    }
    float kv[16];
#pragma unroll
    for (int i = 0; i < 16; ++i) {
      int tp = tp0 + i;
      float k = 0.f;
      if (tp <= t) {
#pragma unroll
        for (int q = 0; q < 4; ++q) {
          float4 lpv = *(const float4*)&Lb[tp * 16 + q * 4];
          float4 fbv = *(const float4*)&cf[tp * 48 + 16 + q * 4];
          k += cv[q].x * __expf(lv[q].x - lpv.x) * fbv.x
             + cv[q].y * __expf(lv[q].y - lpv.y) * fbv.y
             + cv[q].z * __expf(lv[q].z - lpv.z) * fbv.z
             + cv[q].w * __expf(lv[q].w - lpv.w) * fbv.w;
        }
      }
      kv[i] = k;
    }
    bf16x8 lo, hi;
#pragma unroll
    for (int i = 0; i < 8; ++i) { lo[i] = (bf16_t)kv[i]; hi[i] = (bf16_t)kv[8 + i]; }
    unsigned b0 = (unsigned)(t * 128 + tp0 * 2) ^ ((unsigned)(t & 7) << 4);
    unsigned b1 = (unsigned)(t * 128 + tp0 * 2 + 16) ^ ((unsigned)(t & 7) << 4);
    *(bf16x8*)((char*)Km + b0) = lo;
    *(bf16x8*)((char*)Km + b1) = hi;
  }
  __syncthreads();
  int fr = lane & 15, kq = lane >> 4;
  int trow = (wave >> 1) * 32, wc = (wave & 1) * 64;
  f32x4 acc[2][4] = {};
#pragma unroll
  for (int kk = 0; kk < 2; ++kk) {
    int kb = kk * 4 + kq;
    bf16x8 af[2];
#pragma unroll
    for (int mi = 0; mi < 2; ++mi) {
      int row = trow + mi * 16 + fr;
      af[mi] = *(const bf16x8*)((const char*)Km +
                 ((unsigned)(row * 128 + kb * 16) ^ ((unsigned)(row & 7) << 4)));
    }
#pragma unroll
    for (int ni = 0; ni < 4; ++ni) {
      int ch = wc + ni * 16 + fr;
      bf16x8 bfr = *(const bf16x8*)((const char*)Ut +
                     ((unsigned)(ch * 128 + kb * 16) ^ ((unsigned)(ch & 7) << 4)));
#pragma unroll
      for (int mi = 0; mi < 2; ++mi)
        acc[mi][ni] = __builtin_amdgcn_mfma_f32_16x16x32_bf16(af[mi], bfr, acc[mi][ni], 0, 0, 0);
    }
  }
  {
    int s0 = kq * 8;
    bf16x8 cef[2];
    if (s0 < 16) {
#pragma unroll
      for (int mi = 0; mi < 2; ++mi) {
        int t = trow + mi * 16 + fr;
#pragma unroll
        for (int j = 0; j < 8; ++j)
          cef[mi][j] = (bf16_t)(cf[t * 48 + 32 + s0 + j] * __expf(Lb[t * 16 + s0 + j]));
      }
    } else {
#pragma unroll
      for (int mi = 0; mi < 2; ++mi)
#pragma unroll
        for (int j = 0; j < 8; ++j) cef[mi][j] = (bf16_t)0.f;
    }
#pragma unroll
    for (int ni = 0; ni < 4; ++ni) {
      int ch = wc + ni * 16 + fr;
      bf16x8 bhf = *(const bf16x8*)((const char*)Hb + ch * 64 + s0 * 2);
#pragma unroll
      for (int mi = 0; mi < 2; ++mi)
        acc[mi][ni] = __builtin_amdgcn_mfma_f32_16x16x32_bf16(cef[mi], bhf, acc[mi][ni], 0, 0, 0);
    }
  }
  {
    int64_t rowbase = (int64_t)b * 1024 + t0;
    int colbase = g * 128;
#pragma unroll
    for (int mi = 0; mi < 2; ++mi) {
#pragma unroll
      for (int ni = 0; ni < 4; ++ni) {
        int col = colbase + wc + ni * 16 + fr;
#pragma unroll
        for (int j = 0; j < 4; ++j) {
          int t = trow + mi * 16 + kq * 4 + j;
          float sg;
          if (GM) {
            sg = (float)gate_b[(rowbase + t) * 2048 + col];
          } else {
            float gv = gate_f[(rowbase + t) * (int64_t)gstride + col];
            sg = gv / (1.f + __expf(-gv));
          }
          yout[(rowbase + t) * 2048 + col] = (bf16_t)(acc[mi][ni][j] * sg);
        }
      }
    }
  }
}

// ======== epilogue helper (fallback gemm_bt only) ========
template <int EPI>
__device__ __forceinline__ void epi_store(float v, int64_t r, int64_t cn, int N,
                                          float* Cz, const float* bias,
                                          const float* res, bf16_t* obf,
                                          bf16_t* ogate, int z) {
  if (EPI & 1) v += bias[cn];
  if (EPI & 2) v += res[r * N + cn];
  if (EPI & 4) {
    float sv = v / (1.f + __expf(-v));
    if (cn < 2048) obf[r * 2048 + cn] = (bf16_t)sv;
    else ogate[r * 2048 + cn - 2048] = (bf16_t)sv;
  } else if (EPI & 8) {
    obf[r * N + cn] = (bf16_t)(v / (1.f + __expf(-v)));
  } else if (EPI & 16) {
    obf[(int64_t)z * ROWS * N + r * N + cn] = (bf16_t)v;
  } else {
    Cz[r * N + cn] = v;
  }
}

// bijective XCD swizzle over flattened grid (identity if nwg%8 != 0)
__device__ __forceinline__ void xcd_swz(int& bx, int& by, int& bz) {
  int gx = gridDim.x, gy = gridDim.y, gz = gridDim.z;
  int flat = blockIdx.x + gx * (blockIdx.y + gy * blockIdx.z);
  int nwg = gx * gy * gz;
  int swz = flat;
  if ((nwg & 7) == 0) swz = (flat & 7) * (nwg >> 3) + (flat >> 3);
  bx = swz % gx;
  int rem = swz / gx;
  by = rem % gy;
  bz = rem / gy;
}

// ---------------- bf16 GEMM 128x128, double-buffered 2-phase (fallback) -----
template <int EPI>
__global__ __launch_bounds__(256) void gemm_bt(const bf16_t* __restrict__ A,
                                               const bf16_t* __restrict__ Bw,
                                               float* __restrict__ C,
                                               const float* __restrict__ bias,
                                               const float* __restrict__ res,
                                               bf16_t* __restrict__ obf,
                                               bf16_t* __restrict__ ogate,
                                               int N, int Kps) {
  __shared__ bf16_t As[2][128 * 64];
  __shared__ bf16_t Bs[2][128 * 64];
  const int tid = threadIdx.x;
  const int wave = tid >> 6;
  const int lane = tid & 63;
  int bxi, byi, bzi;
  xcd_swz(bxi, byi, bzi);
  const int64_t m0 = (int64_t)byi * 128;
  const int64_t n0 = (int64_t)bxi * 128;
  const int K = Kps * gridDim.z;
  const int kbeg = bzi * Kps;
  float* Cz = C + (int64_t)bzi * ROWS * N;
  const int wm = (wave >> 1) * 64;
  const int wn = (wave & 1) * 64;
  f32x4 acc[4][4] = {};

  const int er = tid >> 3;
  const int ec = (tid * 8) & 63;
  const int fr = lane & 15;
  const int kq = (lane >> 4) * 8;

  auto stage = [&](int buf, int k0) {
#pragma unroll
    for (int i = 0; i < 4; ++i) {
      const bf16_t* ga = A + (m0 + er + i * 32) * K + k0 + ec;
      __builtin_amdgcn_global_load_lds((gvoid_t*)ga,
                                       (lvoid_t*)&As[buf][(i * 256 + wave * 64) * 8],
                                       16, 0, 0);
    }
#pragma unroll
    for (int i = 0; i < 4; ++i) {
      const bf16_t* gb = Bw + (n0 + er + i * 32) * K + k0 + ec;
      __builtin_amdgcn_global_load_lds((gvoid_t*)gb,
                                       (lvoid_t*)&Bs[buf][(i * 256 + wave * 64) * 8],
                                       16, 0, 0);
    }
  };
  auto compute = [&](int buf) {
#pragma unroll
    for (int kk = 0; kk < 2; ++kk) {
      bf16x8 af[4], bv[4];
#pragma unroll
      for (int mi = 0; mi < 4; ++mi)
        af[mi] = *reinterpret_cast<const bf16x8*>(&As[buf][(wm + mi * 16 + fr) * 64 + kk * 32 + kq]);
#pragma unroll
      for (int ni = 0; ni < 4; ++ni)
        bv[ni] = *reinterpret_cast<const bf16x8*>(&Bs[buf][(wn + ni * 16 + fr) * 64 + kk * 32 + kq]);
#pragma unroll
      for (int mi = 0; mi < 4; ++mi)
#pragma unroll
        for (int ni = 0; ni < 4; ++ni)
          acc[mi][ni] = __builtin_amdgcn_mfma_f32_16x16x32_bf16(af[mi], bv[ni], acc[mi][ni], 0, 0, 0);
    }
  };

  const int nk = Kps >> 6;  // assumed even
  stage(0, kbeg);
  asm volatile("s_waitcnt vmcnt(0)" ::: "memory");
  __builtin_amdgcn_s_barrier();
  int kc = kbeg;
  for (int t = 0; t < nk; t += 2) {
    stage(1, kc + 64);
    compute(0);
    asm volatile("s_waitcnt vmcnt(0)" ::: "memory");
    __builtin_amdgcn_s_barrier();
    if (t + 2 < nk) stage(0, kc + 128);
    compute(1);
    asm volatile("s_waitcnt vmcnt(0)" ::: "memory");
    __builtin_amdgcn_s_barrier();
    kc += 128;
  }

  const int crow = (lane >> 4) * 4;
  const int ccol = lane & 15;
#pragma unroll
  for (int mi = 0; mi < 4; ++mi)
#pragma unroll
    for (int ni = 0; ni < 4; ++ni)
#pragma unroll
      for (int j = 0; j < 4; ++j)
        epi_store<EPI>(acc[mi][ni][j], m0 + wm + mi * 16 + crow + j,
                       n0 + wn + ni * 16 + ccol, N, Cz, bias, res, obf, ogate,
                       bzi);
}

// ---------------- param GEMM (128x128, SK=4) + W_out/W_f1/W_f2 conversion ---
__global__ __launch_bounds__(256) void gemm_param_conv(
    const bf16_t* __restrict__ A, const bf16_t* __restrict__ Bw,
    bf16_t* __restrict__ pout,
    const float* __restrict__ W_out, const float* __restrict__ W_f1,
    const float* __restrict__ W_f2,
    bf16_t* o_out, bf16_t* o_f1, bf16_t* o_f2) {
  __shared__ bf16_t As[2][128 * 64];
  __shared__ bf16_t Bs[2][128 * 64];
  const int tid = threadIdx.x;
  if (blockIdx.x >= 320) {
    conv3(blockIdx.x - 320, tid, W_out, W_f1, W_f2, o_out, o_f1, o_f2);
    return;
  }
  const int flat = blockIdx.x;
  const int swz = (flat & 7) * 40 + (flat >> 3);  // 320 % 8 == 0, bijective
  const int bxi = swz % 5;
  const int byi = (swz / 5) % 16;
  const int bzi = swz / 80;
  const int wave = tid >> 6;
  const int lane = tid & 63;
  const int64_t m0 = (int64_t)byi * 128;
  const int64_t n0 = (int64_t)bxi * 128;
  const int K = 2048, Kps = 512;
  const int kbeg = bzi * Kps;
  const int wm = (wave >> 1) * 64;
  const int wn = (wave & 1) * 64;
  f32x4 acc[4][4] = {};
  const int er = tid >> 3;
  const int ec = (tid * 8) & 63;
  const int fr = lane & 15;
  const int kq = (lane >> 4) * 8;

  auto stage = [&](int buf, int k0) {
#pragma unroll
    for (int i = 0; i < 4; ++i) {
      const bf16_t* ga = A + (m0 + er + i * 32) * K + k0 + ec;
      __builtin_amdgcn_global_load_lds((gvoid_t*)ga,
                                       (lvoid_t*)&As[buf][(i * 256 + wave * 64) * 8],
                                       16, 0, 0);
    }
#pragma unroll
    for (int i = 0; i < 4; ++i) {
      const bf16_t* gb = Bw + (n0 + er + i * 32) * K + k0 + ec;
      __builtin_amdgcn_global_load_lds((gvoid_t*)gb,
                                       (lvoid_t*)&Bs[buf][(i * 256 + wave * 64) * 8],
                                       16, 0, 0);
    }
  };
  auto compute = [&](int buf) {
#pragma unroll
    for (int kk = 0; kk < 2; ++kk) {
      bf16x8 af[4], bv[4];
#pragma unroll
      for (int mi = 0; mi < 4; ++mi)
        af[mi] = *reinterpret_cast<const bf16x8*>(&As[buf][(wm + mi * 16 + fr) * 64 + kk * 32 + kq]);
#pragma unroll
      for (int ni = 0; ni < 4; ++ni)
        bv[ni] = *reinterpret_cast<const bf16x8*>(&Bs[buf][(wn + ni * 16 + fr) * 64 + kk * 32 + kq]);
#pragma unroll
      for (int mi = 0; mi < 4; ++mi)
#pragma unroll
        for (int ni = 0; ni < 4; ++ni)
          acc[mi][ni] = __builtin_amdgcn_mfma_f32_16x16x32_bf16(af[mi], bv[ni], acc[mi][ni], 0, 0, 0);
    }
  };

  const int nk = Kps >> 6;  // 8
  stage(0, kbeg);
  asm volatile("s_waitcnt vmcnt(0)" ::: "memory");
  __builtin_amdgcn_s_barrier();
  int kc = kbeg;
  for (int t = 0; t < nk; t += 2) {
    stage(1, kc + 64);
    compute(0);
    asm volatile("s_waitcnt vmcnt(0)" ::: "memory");
    __builtin_amdgcn_s_barrier();
    if (t + 2 < nk) stage(0, kc + 128);
    compute(1);
    asm volatile("s_waitcnt vmcnt(0)" ::: "memory");
    __builtin_amdgcn_s_barrier();
    kc += 128;
  }

  const int crow = (lane >> 4) * 4;
  const int ccol = lane & 15;
  bf16_t* pz = pout + (int64_t)bzi * ROWS * PPAD;
#pragma unroll
  for (int mi = 0; mi < 4; ++mi)
#pragma unroll
    for (int ni = 0; ni < 4; ++ni)
#pragma unroll
      for (int j = 0; j < 4; ++j) {
        int64_t r = m0 + wm + mi * 16 + crow + j;
        int64_t cn = n0 + wn + ni * 16 + ccol;
        pz[r * PPAD + cn] = (bf16_t)acc[mi][ni][j];
      }
}

// ---------------- bf16 GEMM 128x128, 8-wave, 4-phase counted pipeline -------
// 64KB LDS -> 2 blocks/CU. Per K-tile: 4 phases of
// {4 ds_read -> lgkm(0) -> barrier -> setprio+4 MFMA -> barrier}; stage(t+2)
// issued in phase 3 after buf-reads proven complete; vmcnt(4) once per tile.
template <int EPI>
__global__ __launch_bounds__(512, 4) void gemm_big(const bf16_t* __restrict__ A,
                                                   const bf16_t* __restrict__ Bw,
                                                   float* __restrict__ C,
                                                   const float* __restrict__ bias,
                                                   const float* __restrict__ res,
                                                   bf16_t* __restrict__ obf,
                                                   bf16_t* __restrict__ ogate,
                                                   int N, int Kps) {
  __shared__ bf16_t As[2][128 * 64];
  __shared__ bf16_t Bs[2][128 * 64];
  const int tid = threadIdx.x;
  const int wave = tid >> 6;
  const int lane = tid & 63;
  int bxi, byi, bzi;
  xcd_swz(bxi, byi, bzi);
  const int64_t m0 = (int64_t)byi * 128;
  const int64_t n0 = (int64_t)bxi * 128;
  const int K = Kps * gridDim.z;
  const int kbeg = bzi * Kps;
  float* Cz = C + (int64_t)bzi * ROWS * N;
  (void)Cz; (void)res;
  const int wm = (wave >> 1) * 32;   // 4 M-wave rows of 32
  const int wc = (wave & 1) * 64;    // 2 N-wave cols of 64
  const int fr = lane & 15;
  const int kq16 = (lane >> 4) * 16;
  const int er = tid >> 3;                              // staging row 0..63
  const int ec_sw = ((tid & 7) * 8) ^ ((er & 7) << 3);  // swizzled src col
  f32x4 acc[2][4] = {};

  auto stage = [&](int buf, int k0) {
#pragma unroll
    for (int i = 0; i < 2; ++i) {
      const bf16_t* ga = A + (m0 + er + i * 64) * K + k0 + ec_sw;
      __builtin_amdgcn_global_load_lds((gvoid_t*)ga,
          (lvoid_t*)((char*)&As[buf][0] + i * 8192 + wave * 1024), 16, 0, 0);
    }
#pragma unroll
    for (int i = 0; i < 2; ++i) {
      const bf16_t* gb = Bw + (n0 + er + i * 64) * K + k0 + ec_sw;
      __builtin_amdgcn_global_load_lds((gvoid_t*)gb,
          (lvoid_t*)((char*)&Bs[buf][0] + i * 8192 + wave * 1024), 16, 0, 0);
    }
  };
  // read fragments for phase (kk, half h): af[2], bf half [2]
  auto rd_a = [&](int buf, int kk, bf16x8* a) {
#pragma unroll
    for (int mi = 0; mi < 2; ++mi) {
      int r = wm + mi * 16 + fr;
      a[mi] = *(const bf16x8*)((const char*)&As[buf][0] + r * 128 +
                ((kk * 64 + kq16) ^ ((r & 7) << 4)));
    }
  };
  auto rd_b = [&](int buf, int kk, int h, bf16x8* bv) {
#pragma unroll
    for (int ni = 0; ni < 2; ++ni) {
      int r = wc + (h * 2 + ni) * 16 + fr;
      bv[ni] = *(const bf16x8*)((const char*)&Bs[buf][0] + r * 128 +
                 ((kk * 64 + kq16) ^ ((r & 7) << 4)));
    }
  };

  const int nk = Kps >> 6;
  stage(0, kbeg);
  if (nk > 1) {
    stage(1, kbeg + 64);
    asm volatile("s_waitcnt vmcnt(4)" ::: "memory");
  } else {
    asm volatile("s_waitcnt vmcnt(0)" ::: "memory");
  }
  __builtin_amdgcn_s_barrier();
  __builtin_amdgcn_sched_barrier(0);

  for (int t = 0; t < nk; ++t) {
    const int buf = t & 1;
#pragma unroll
    for (int ph = 0; ph < 4; ++ph) {
      const int kk = ph >> 1, h = ph & 1;
      bf16x8 a[2], bv[2];
      rd_a(buf, kk, a);
      rd_b(buf, kk, h, bv);
      asm volatile("s_waitcnt lgkmcnt(0)" ::: "memory");
      __builtin_amdgcn_sched_barrier(0);
      __builtin_amdgcn_s_barrier();
      __builtin_amdgcn_sched_barrier(0);
      if (ph == 3 && t + 2 < nk) stage(buf, kbeg + (t + 2) * 64);
      __builtin_amdgcn_s_setprio(1);
#pragma unroll
      for (int mi = 0; mi < 2; ++mi)
#pragma unroll
        for (int ni = 0; ni < 2; ++ni)
          acc[mi][h * 2 + ni] = __builtin_amdgcn_mfma_f32_16x16x32_bf16(
              a[mi], bv[ni], acc[mi][h * 2 + ni], 0, 0, 0);
      __builtin_amdgcn_s_setprio(0);
      __builtin_amdgcn_sched_barrier(0);
      __builtin_amdgcn_s_barrier();
      __builtin_amdgcn_sched_barrier(0);
    }
    if (t + 1 < nk) {
      if (t + 2 < nk) asm volatile("s_waitcnt vmcnt(4)" ::: "memory");
      else            asm volatile("s_waitcnt vmcnt(0)" ::: "memory");
      __builtin_amdgcn_s_barrier();        // stage(t+1) landed
      __builtin_amdgcn_sched_barrier(0);
    }
  }

  // ---- coalesced epilogue: per-wave 32x64 bf16 tile in dead Bs, XOR-swizzled
  __syncthreads();
  {
    char* ep = (char*)&Bs[0][0] + wave * 4096;  // 32 rows x 128B
    const int crow = (lane >> 4) * 4;
    const int ccol = lane & 15;
#pragma unroll
    for (int mi = 0; mi < 2; ++mi) {
#pragma unroll
      for (int ni = 0; ni < 4; ++ni) {
        int lc = ni * 16 + ccol;
        float bv = (EPI & 1) ? bias[n0 + wc + lc] : 0.f;
#pragma unroll
        for (int j = 0; j < 4; ++j) {
          int lr = mi * 16 + crow + j;
          float v = acc[mi][ni][j] + bv;
          if (EPI & 12) v = v / (1.f + __expf(-v));
          *(bf16_t*)(ep + lr * 128 + ((lc * 2) ^ ((lr & 7) << 4))) = (bf16_t)v;
        }
      }
    }
#pragma unroll
    for (int i = 0; i < 4; ++i) {
      int idx = i * 64 + lane;
      int row = idx >> 3;
      int grp = idx & 7;
      bf16x8 v = *(const bf16x8*)(ep + row * 128 + ((grp * 16) ^ ((row & 7) << 4)));
      int64_t r = m0 + wm + row;
      int64_t cn = n0 + wc + grp * 8;
      bf16_t* dst;
      if (EPI & 4) {
        dst = (cn < 2048) ? (obf + r * 2048 + cn) : (ogate + r * 2048 + cn - 2048);
      } else if (EPI & 16) {
        dst = obf + (int64_t)bzi * ROWS * N + r * N + cn;
      } else {
        dst = obf + r * N + cn;
      }
      *(bf16x8*)dst = v;
    }
  }
}

extern "C" void kernel_launch(void* const* d_in, const int* in_sizes, int n_in,
                              void* d_out, int out_size, void* d_ws, size_t ws_size,
                              hipStream_t stream) {
  const float* x       = (const float*)d_in[0];
  const float* A_log   = (const float*)d_in[1];
  const float* g1      = (const float*)d_in[2];
  const float* g2      = (const float*)d_in[3];
  const float* W_in    = (const float*)d_in[4];
  const float* W_param = (const float*)d_in[5];
  const float* W_out   = (const float*)d_in[6];
  const float* W_ffn1  = (const float*)d_in[7];
  const float* b_ffn1  = (const float*)d_in[8];
  const float* W_ffn2  = (const float*)d_in[9];
  const float* b_ffn2  = (const float*)d_in[10];
  float* out = (float*)d_out;

  char* ws = (char*)d_ws;
  size_t off = 0;
  auto alloc = [&](size_t bytes) {
    char* p = ws + off;
    off += (bytes + 255) & ~(size_t)255;
    return p;
  };
  bf16_t* wb_in  = (bf16_t*)alloc(4096ull * 1024 * 2);
  bf16_t* wb_par = (bf16_t*)alloc((size_t)PPAD * 2048 * 2);
  bf16_t* wb_out = (bf16_t*)alloc(1024ull * 2048 * 2);
  bf16_t* wb_f1  = (bf16_t*)alloc(4096ull * 1024 * 2);
  bf16_t* wb_f2  = (bf16_t*)alloc(1024ull * 4096 * 2);
  bf16_t* zbuf   = (bf16_t*)alloc(2048ull * 1024 * 2);   // z, later h2
  float*  xzg    = (float*)alloc(2048ull * 4096 * 4);    // sgate bf16 (sk) / fp32 (fallback)
  float*  params = (float*)alloc(2048ull * PPAD * 4);    // fallback GEMM out; S/Etot overlay
  float*  ssmp   = (float*)alloc(32ull * 1024 * 48 * 4); // fallback only
  float*  xmid   = (float*)alloc(2048ull * 1024 * 4);    // bf16 (sk) / fp32 (fallback)
  char*   regA   = alloc(2048ull * 4096 * 2);            // 16MB union
  bf16_t* xz_act = (bf16_t*)regA;
  bf16_t* y_b16  = (bf16_t*)(regA + 2048ull * 2048 * 2);
  bf16_t* f_act  = (bf16_t*)regA;
  bf16_t* sgate  = (bf16_t*)xzg;                         // [2048][2048] bf16 (sk)
  bf16_t* xmid_b = (bf16_t*)xmid;                        // bf16 residual (sk)
  float* Sbuf = params;
  float* Etot = params + 32ull * 16 * 16 * 128;
  float*  psum = (float*)alloc(4ull * ROWS * 1024 * 4);  // fp32 partials (fallback)
  bf16_t* pb16 = (bf16_t*)psum;                          // bf16 partials overlay
  const bool sk = (off <= ws_size);

  dim3 b256(256), b512(512);
  // W_in/W_param -> bf16 + z = rmsnorm(x,g1)
  prep0<<<7424, b256, 0, stream>>>(W_in, W_param, wb_in, wb_par, x, g1, zbuf);

  if (sk) {
    // xz|gate = z @ W_in^T, fused: silu(xz)->xz_act, silu(gate)->sgate (bf16)
    gemm_big<4><<<dim3(32, 16), b512, 0, stream>>>(zbuf, wb_in, psum, nullptr, nullptr, xz_act, sgate, 4096, 1024);
    // param partials (bf16, SK=4) + W_out/W_f1/W_f2 conversion riding along
    gemm_param_conv<<<10560, b256, 0, stream>>>(xz_act, wb_par, pb16,
                                                W_out, W_ffn1, W_ffn2,
                                                wb_out, wb_f1, wb_f2);
    // chunked scan (coefficient prep inlined; combine inlined in ssm_out)
    ssm_chunk<1><<<480, b256, 0, stream>>>(nullptr, pb16, A_log, xz_act, Sbuf, Etot);
    ssm_out<1, 1><<<512, b256, 0, stream>>>(nullptr, pb16, A_log, xz_act, Sbuf, Etot, nullptr, sgate, 2048, y_b16);
    // xmid = x + y @ W_out^T (SK=4, bf16 partials) fused reduce+rmsnorm
    gemm_big<16><<<dim3(8, 16, 4), b512, 0, stream>>>(y_b16, wb_out, psum, nullptr, nullptr, pb16, nullptr, 1024, 512);
    reduce_rms<<<2048, b256, 0, stream>>>(pb16, x, g2, xmid_b, zbuf);
    // ffn1 + bias + silu -> f_act bf16 (fused)
    gemm_big<9><<<dim3(32, 16), b512, 0, stream>>>(zbuf, wb_f1, psum, b_ffn1, nullptr, f_act, nullptr, 4096, 1024);
    // out = xmid + b_ffn2 + f_act @ W_ffn2^T (SK=4, bf16 partials)
    gemm_big<16><<<dim3(8, 16, 4), b512, 0, stream>>>(f_act, wb_f2, psum, nullptr, nullptr, pb16, nullptr, 1024, 1024);
    reduce_bias<<<2048, b256, 0, stream>>>(pb16, xmid_b, b_ffn2, out);
  } else {
    cvt3_k<<<10240, b256, 0, stream>>>(W_out, W_ffn1, W_ffn2, wb_out, wb_f1, wb_f2);
    gemm_bt<0><<<dim3(32, 16), b256, 0, stream>>>(zbuf, wb_in, xzg, nullptr, nullptr, nullptr, nullptr, 4096, 1024);
    silu_cvt<<<4096, b256, 0, stream>>>(xzg, xz_act, 4096, 2048);
    gemm_bt<0><<<dim3(PPAD / 128, 16), b256, 0, stream>>>(xz_act, wb_par, params, nullptr, nullptr, nullptr, nullptr, PPAD, 2048);
    ssm_prep<<<128, b256, 0, stream>>>(params, A_log, ssmp);
    ssm_chunk<0><<<480, b256, 0, stream>>>(ssmp, nullptr, A_log, xz_act, Sbuf, Etot);
    ssm_out<0, 0><<<512, b256, 0, stream>>>(ssmp, nullptr, A_log, xz_act, Sbuf, Etot, xzg + 2048, nullptr, 4096, y_b16);
    gemm_bt<2><<<dim3(8, 16), b256, 0, stream>>>(y_b16, wb_out, xmid, nullptr, x, nullptr, nullptr, 1024, 2048);
    rmsnorm_k<<<2048, b256, 0, stream>>>(xmid, g2, zbuf);
    gemm_bt<1><<<dim3(32, 16), b256, 0, stream>>>(zbuf, wb_f1, xzg, b_ffn1, nullptr, nullptr, nullptr, 4096, 1024);
    silu_cvt<<<8192, b256, 0, stream>>>(xzg, f_act, 4096, 4096);
    gemm_bt<3><<<dim3(8, 16), b256, 0, stream>>>(f_act, wb_f2, out, b_ffn2, xmid, nullptr, nullptr, 1024, 4096);
  }
}

// Round 13
// 168.878 us; speedup vs baseline: 1.0737x; 1.0737x over previous
//
#include <hip/hip_runtime.h>
#include <hip/hip_bf16.h>
#include <stdint.h>

// MambaBlock: B=2, T=1024, D_MODEL=1024, D_INNER=2048, GROUPS=16, D_STATE=16
#define ROWS 2048      // B*T
#define DM   1024
#define DI   2048
#define PPAD 640       // 528 param rows padded to 5*128

typedef __bf16 bf16_t;
typedef __attribute__((ext_vector_type(8))) __bf16 bf16x8;
typedef __attribute__((ext_vector_type(4))) __bf16 bf16x4;
typedef __attribute__((ext_vector_type(4))) float f32x4;
typedef __attribute__((address_space(1))) void gvoid_t;
typedef __attribute__((address_space(3))) void lvoid_t;

// ---------------- prep0: W_in + W_param -> bf16, z = rmsnorm(x,g1) ----------
__global__ __launch_bounds__(256) void prep0(const float* __restrict__ W_in,
                                             const float* __restrict__ W_param,
                                             bf16_t* o_in, bf16_t* o_par,
                                             const float* __restrict__ x,
                                             const float* __restrict__ g1,
                                             bf16_t* __restrict__ zb) {
  int tid = threadIdx.x;
  if (blockIdx.x >= 5376) {  // rmsnorm
    int row = blockIdx.x - 5376;
    const float4 v = *(const float4*)(x + (int64_t)row * DM + tid * 4);
    float ss = v.x * v.x + v.y * v.y + v.z * v.z + v.w * v.w;
#pragma unroll
    for (int o = 32; o; o >>= 1) ss += __shfl_xor(ss, o, 64);
    __shared__ float red[4];
    if ((tid & 63) == 0) red[tid >> 6] = ss;
    __syncthreads();
    float tot = red[0] + red[1] + red[2] + red[3];
    float sc = rsqrtf(tot * (1.0f / DM) + 1e-6f);
    const float4 gv = *(const float4*)(g1 + tid * 4);
    bf16_t* o = zb + (int64_t)row * DM + tid * 4;
    o[0] = (bf16_t)(v.x * sc * gv.x);
    o[1] = (bf16_t)(v.y * sc * gv.y);
    o[2] = (bf16_t)(v.z * sc * gv.z);
    o[3] = (bf16_t)(v.w * sc * gv.w);
    return;
  }
  if (blockIdx.x >= 4096) {  // W_param, zero-padded 528 -> 640 rows
    int64_t e = (((int64_t)(blockIdx.x - 4096)) * 256 + tid) * 4;
    int row = (int)(e >> 11), col = (int)(e & 2047);
    float4 v = make_float4(0.f, 0.f, 0.f, 0.f);
    if (row < 528) v = *(const float4*)(W_param + (int64_t)row * 2048 + col);
    bf16_t* o = o_par + e;
    o[0] = (bf16_t)v.x; o[1] = (bf16_t)v.y; o[2] = (bf16_t)v.z; o[3] = (bf16_t)v.w;
    return;
  }
  int64_t e = ((int64_t)blockIdx.x * 256 + tid) * 4;
  float4 v = *(const float4*)(W_in + e);
  bf16_t* o = o_in + e;
  o[0] = (bf16_t)v.x; o[1] = (bf16_t)v.y; o[2] = (bf16_t)v.z; o[3] = (bf16_t)v.w;
}

// ---------------- conversion of W_out/W_f1/W_f2 (10240 blocks) --------------
__device__ __forceinline__ void conv3(int64_t c, int tid,
                                      const float* __restrict__ W_out,
                                      const float* __restrict__ W_f1,
                                      const float* __restrict__ W_f2,
                                      bf16_t* o_out, bf16_t* o_f1, bf16_t* o_f2) {
  const float* src; bf16_t* dst; int64_t e;
  if (c < 2048) { e = (c * 256 + tid) * 4; src = W_out; dst = o_out; }
  else if (c < 6144) { e = ((c - 2048) * 256 + tid) * 4; src = W_f1; dst = o_f1; }
  else { e = ((c - 6144) * 256 + tid) * 4; src = W_f2; dst = o_f2; }
  float4 v = *(const float4*)(src + e);
  bf16_t* o = dst + e;
  o[0] = (bf16_t)v.x; o[1] = (bf16_t)v.y; o[2] = (bf16_t)v.z; o[3] = (bf16_t)v.w;
}

__global__ __launch_bounds__(256) void cvt3_k(const float* __restrict__ W_out,
                                              const float* __restrict__ W_f1,
                                              const float* __restrict__ W_f2,
                                              bf16_t* o_out, bf16_t* o_f1,
                                              bf16_t* o_f2) {
  conv3(blockIdx.x, threadIdx.x, W_out, W_f1, W_f2, o_out, o_f1, o_f2);
}

// ---------------- rmsnorm (fallback) ----------------
__global__ __launch_bounds__(256) void rmsnorm_k(const float* __restrict__ x,
                                                 const float* __restrict__ g,
                                                 bf16_t* __restrict__ out) {
  int row = blockIdx.x;
  int tid = threadIdx.x;
  const float4 v = *(const float4*)(x + (int64_t)row * DM + tid * 4);
  float ss = v.x * v.x + v.y * v.y + v.z * v.z + v.w * v.w;
#pragma unroll
  for (int o = 32; o; o >>= 1) ss += __shfl_xor(ss, o, 64);
  __shared__ float red[4];
  if ((tid & 63) == 0) red[tid >> 6] = ss;
  __syncthreads();
  float tot = red[0] + red[1] + red[2] + red[3];
  float sc = rsqrtf(tot * (1.0f / DM) + 1e-6f);
  const float4 gv = *(const float4*)(g + tid * 4);
  bf16_t* o = out + (int64_t)row * DM + tid * 4;
  o[0] = (bf16_t)(v.x * sc * gv.x);
  o[1] = (bf16_t)(v.y * sc * gv.y);
  o[2] = (bf16_t)(v.z * sc * gv.z);
  o[3] = (bf16_t)(v.w * sc * gv.w);
}

// ---------------- silu + fp32 -> bf16 (fallback) ----------------
__global__ __launch_bounds__(256) void silu_cvt(const float* __restrict__ in,
                                                bf16_t* __restrict__ out,
                                                int in_stride, int ncols) {
  int64_t e = ((int64_t)blockIdx.x * 256 + threadIdx.x) * 4;
  int row = (int)(e / ncols);
  int col = (int)(e % ncols);
  const float4 v = *(const float4*)(in + (int64_t)row * in_stride + col);
  bf16_t* o = out + e;
  o[0] = (bf16_t)(v.x / (1.f + expf(-v.x)));
  o[1] = (bf16_t)(v.y / (1.f + expf(-v.y)));
  o[2] = (bf16_t)(v.z / (1.f + expf(-v.z)));
  o[3] = (bf16_t)(v.w / (1.f + expf(-v.w)));
}

// ---------------- standalone ssm_prep (fallback only) ----------------------
__global__ __launch_bounds__(256) void ssm_prep(const float* __restrict__ params,
                                                const float* __restrict__ A_log,
                                                float* __restrict__ ssmp) {
  int gid = blockIdx.x * 256 + threadIdx.x;  // 32 * 1024
  int bg = gid >> 10, t = gid & 1023;
  int b = bg >> 4, g = bg & 15;
  const float* pr = params + (int64_t)(b * 1024 + t) * PPAD + g * 33;
  float raw = pr[0];
  float delta = raw > 0.f ? raw + log1pf(expf(-raw)) : log1pf(expf(raw));
  float* o = ssmp + (int64_t)gid * 48;
#pragma unroll
  for (int s = 0; s < 16; ++s) {
    float A = -expf(A_log[s]);
    float dA = delta * A;
    dA = fminf(10.f, fmaxf(-10.f, dA));
    float e = expf(dA);
    float frac = (fabsf(dA) < 1e-4f) ? delta : (e - 1.f) / (A + 1e-12f);
    o[s] = dA;
    o[16 + s] = frac * pr[1 + s];
    o[32 + s] = pr[17 + s];
  }
}

// ---------------- split-K reduce (bf16 partials) + residual + rmsnorm -------
__global__ __launch_bounds__(256) void reduce_rms(const bf16_t* __restrict__ P,
                                                  const float* __restrict__ x,
                                                  const float* __restrict__ g,
                                                  bf16_t* __restrict__ xmid,
                                                  bf16_t* __restrict__ zb) {
  int row = blockIdx.x;
  int tid = threadIdx.x;
  int64_t base = (int64_t)row * DM + tid * 4;
  float4 v = *(const float4*)(x + base);
#pragma unroll
  for (int p = 0; p < 4; ++p) {
    bf16x4 pv = *(const bf16x4*)(P + (int64_t)p * ROWS * DM + base);
    v.x += (float)pv[0]; v.y += (float)pv[1]; v.z += (float)pv[2]; v.w += (float)pv[3];
  }
  bf16x4 xm;
  xm[0] = (bf16_t)v.x; xm[1] = (bf16_t)v.y; xm[2] = (bf16_t)v.z; xm[3] = (bf16_t)v.w;
  *(bf16x4*)(xmid + base) = xm;
  float ss = v.x * v.x + v.y * v.y + v.z * v.z + v.w * v.w;
#pragma unroll
  for (int o = 32; o; o >>= 1) ss += __shfl_xor(ss, o, 64);
  __shared__ float red[4];
  if ((tid & 63) == 0) red[tid >> 6] = ss;
  __syncthreads();
  float tot = red[0] + red[1] + red[2] + red[3];
  float sc = rsqrtf(tot * (1.0f / DM) + 1e-6f);
  const float4 gv = *(const float4*)(g + tid * 4);
  bf16_t* o = zb + base;
  o[0] = (bf16_t)(v.x * sc * gv.x);
  o[1] = (bf16_t)(v.y * sc * gv.y);
  o[2] = (bf16_t)(v.z * sc * gv.z);
  o[3] = (bf16_t)(v.w * sc * gv.w);
}

__global__ __launch_bounds__(256) void reduce_bias(const bf16_t* __restrict__ P,
                                                   const bf16_t* __restrict__ res,
                                                   const float* __restrict__ bias,
                                                   float* __restrict__ out) {
  int64_t e = ((int64_t)blockIdx.x * 256 + threadIdx.x) * 4;
  int col = (int)(e % DM);
  bf16x4 rv = *(const bf16x4*)(res + e);
  const float4 bv = *(const float4*)(bias + col);
  float4 v = make_float4((float)rv[0] + bv.x, (float)rv[1] + bv.y,
                         (float)rv[2] + bv.z, (float)rv[3] + bv.w);
#pragma unroll
  for (int p = 0; p < 4; ++p) {
    bf16x4 pv = *(const bf16x4*)(P + (int64_t)p * ROWS * DM + e);
    v.x += (float)pv[0]; v.y += (float)pv[1]; v.z += (float)pv[2]; v.w += (float)pv[3];
  }
  *(float4*)(out + e) = v;
}

// inline prep: compute 64 rows of coefficients into cf[64*48] from bf16
// split-K partials (4 parts). cf row t: { dA[16], frac*b[16], c[16] }.
__device__ __forceinline__ void prep_rows(const bf16_t* __restrict__ pb,
                                          const float* __restrict__ A_log,
                                          float* cf, int b, int g, int t0,
                                          int tid) {
  if (tid >= 64) return;
  int t = tid;
  int64_t row = (int64_t)(b * 1024) + t0 + t;
  float acc[33];
#pragma unroll
  for (int i = 0; i < 33; ++i) acc[i] = 0.f;
#pragma unroll
  for (int p = 0; p < 4; ++p) {
    const bf16_t* pr = pb + (int64_t)p * ROWS * PPAD + row * PPAD + g * 33;
#pragma unroll
    for (int i = 0; i < 33; ++i) acc[i] += (float)pr[i];
  }
  float raw = acc[0];
  float delta = raw > 0.f ? raw + log1pf(expf(-raw)) : log1pf(expf(raw));
  float* o = cf + t * 48;
#pragma unroll
  for (int s = 0; s < 16; ++s) {
    float A = -expf(A_log[s]);
    float dA = delta * A;
    dA = fminf(10.f, fmaxf(-10.f, dA));
    float e = expf(dA);
    float frac = (fabsf(dA) < 1e-4f) ? delta : (e - 1.f) / (A + 1e-12f);
    o[s] = dA;
    o[16 + s] = frac * acc[1 + s];
    o[32 + s] = acc[17 + s];
  }
}

// Ut layout: element (ch, t) at byte ch*128 + ((t*2) ^ ((ch&7)<<4))

// ---------------- Phase A: per-chunk boundary operator (MFMA) ---------------
// grid 480: chunks 0..14 only (chunk 15's S/Etot are never consumed)
template <int PREP>
__global__ __launch_bounds__(256) void ssm_chunk(const float* __restrict__ ssmp,
                                                 const bf16_t* __restrict__ pb,
                                                 const float* __restrict__ A_log,
                                                 const bf16_t* __restrict__ u,
                                                 float* __restrict__ S,
                                                 float* __restrict__ Etot) {
  __shared__ __align__(16) float cf[64 * 48];
  __shared__ __align__(16) float Lb[64 * 16];
  __shared__ __align__(16) bf16_t wl[16 * 64];
  __shared__ __align__(16) bf16_t Ut[128 * 64];
  int bg = blockIdx.x / 15, c = blockIdx.x % 15;
  int bgc = bg * 16 + c;
  int b = bg >> 4, g = bg & 15;
  int t0 = c * 64;
  int tid = threadIdx.x;
  {
    int lt = tid >> 4;
    int c8 = (tid & 15) * 8;
#pragma unroll
    for (int p = 0; p < 4; ++p) {
      int t = p * 16 + lt;
      bf16x8 v = *(const bf16x8*)(u + ((int64_t)(b * 1024) + t0 + t) * 2048 + g * 128 + c8);
#pragma unroll
      for (int j = 0; j < 8; ++j)
        Ut[(c8 + j) * 64 + (((t >> 3) ^ j) << 3) + (t & 7)] = v[j];
    }
  }
  if (PREP) {
    prep_rows(pb, A_log, cf, b, g, t0, tid);
  } else {
    const float4* src = (const float4*)(ssmp + ((int64_t)bg * 1024 + t0) * 48);
    float4* dst = (float4*)cf;
#pragma unroll
    for (int i = 0; i < 3; ++i) dst[i * 256 + tid] = src[i * 256 + tid];
  }
  __syncthreads();
  if (tid < 16) {
    float l = 0.f;
    for (int t = 0; t < 64; ++t) { l += cf[t * 48 + tid]; Lb[t * 16 + tid] = l; }
  }
  __syncthreads();
  {
    int s = tid >> 4, tb4 = (tid & 15) * 4;
    float lend = Lb[63 * 16 + s];
    bf16x4 wv;
#pragma unroll
    for (int j = 0; j < 4; ++j) {
      int t = tb4 + j;
      wv[j] = (bf16_t)(__expf(lend - Lb[t * 16 + s]) * cf[t * 48 + 16 + s]);
    }
    unsigned byo = (unsigned)(s * 128 + tb4 * 2) ^ ((unsigned)(s & 7) << 4);
    *(bf16x4*)((char*)wl + byo) = wv;
    if (tid < 16) Etot[(int64_t)bgc * 16 + tid] = __expf(Lb[63 * 16 + tid]);
  }
  __syncthreads();
  {
    int lane = tid & 63, wave = tid >> 6;
    int fr = lane & 15, kq = lane >> 4;
    f32x4 acc2[2] = {};
#pragma unroll
    for (int kk = 0; kk < 2; ++kk) {
      int kb = kk * 4 + kq;
      bf16x8 af = *(const bf16x8*)((const char*)wl +
                    ((unsigned)(fr * 128 + kb * 16) ^ ((unsigned)(fr & 7) << 4)));
#pragma unroll
      for (int q = 0; q < 2; ++q) {
        int ch = (wave * 2 + q) * 16 + fr;
        bf16x8 bfr = *(const bf16x8*)((const char*)Ut +
                       ((unsigned)(ch * 128 + kb * 16) ^ ((unsigned)(ch & 7) << 4)));
        acc2[q] = __builtin_amdgcn_mfma_f32_16x16x32_bf16(af, bfr, acc2[q], 0, 0, 0);
      }
    }
    float* Sp = S + (int64_t)bgc * 2048;
#pragma unroll
    for (int q = 0; q < 2; ++q) {
      int ch = (wave * 2 + q) * 16 + fr;
#pragma unroll
      for (int j = 0; j < 4; ++j) Sp[(kq * 4 + j) * 128 + ch] = acc2[q][j];
    }
  }
}

// ---------------- Phase C: combine (inline) + y = tril(K)@U + ce@H + gate ---
template <int PREP, int GM>
__global__ __launch_bounds__(256) void ssm_out(const float* __restrict__ ssmp,
                                               const bf16_t* __restrict__ pb,
                                               const float* __restrict__ A_log,
                                               const bf16_t* __restrict__ u,
                                               const float* __restrict__ S,
                                               const float* __restrict__ Etot,
                                               const float* __restrict__ gate_f,
                                               const bf16_t* __restrict__ gate_b,
                                               int gstride,
                                               bf16_t* __restrict__ yout) {
  __shared__ __align__(16) float cf[64 * 48];
  __shared__ __align__(16) float Lb[64 * 16];
  __shared__ __align__(16) bf16_t Km[64 * 64];
  __shared__ __align__(16) bf16_t Ut[128 * 64];
  __shared__ __align__(16) bf16_t Hb[128 * 32];
  int bgc = blockIdx.x;
  int bg = bgc >> 4, c = bgc & 15;
  int b = bg >> 4, g = bg & 15;
  int t0 = c * 64;
  int tid = threadIdx.x;
  int lane = tid & 63, wave = tid >> 6;
  {
    int lt = tid >> 4;
    int c8 = (tid & 15) * 8;
#pragma unroll
    for (int p = 0; p < 4; ++p) {
      int t = p * 16 + lt;
      bf16x8 v = *(const bf16x8*)(u + ((int64_t)(b * 1024) + t0 + t) * 2048 + g * 128 + c8);
#pragma unroll
      for (int j = 0; j < 8; ++j)
        Ut[(c8 + j) * 64 + (((t >> 3) ^ j) << 3) + (t & 7)] = v[j];
    }
  }
  // inline sequential combine over preceding chunks -> Hb[ch][s] (bf16)
  {
    int ch = tid & 127, s0 = (tid >> 7) * 8;
    const float* Sp = S + (int64_t)(bg * 16) * 2048;
    const float* Ep = Etot + (int64_t)(bg * 16) * 16;
    float h[8];
#pragma unroll
    for (int j = 0; j < 8; ++j) h[j] = 0.f;
    for (int cc = 0; cc < c; ++cc) {
#pragma unroll
      for (int j = 0; j < 8; ++j)
        h[j] = Ep[cc * 16 + s0 + j] * h[j] +
               Sp[(int64_t)cc * 2048 + (s0 + j) * 128 + ch];
    }
#pragma unroll
    for (int j = 0; j < 8; ++j) {
      Hb[ch * 32 + s0 + j] = (bf16_t)h[j];
      Hb[ch * 32 + 16 + s0 + j] = (bf16_t)0.f;
    }
  }
  if (PREP) {
    prep_rows(pb, A_log, cf, b, g, t0, tid);
  } else {
    const float4* src = (const float4*)(ssmp + ((int64_t)bg * 1024 + t0) * 48);
    float4* dst = (float4*)cf;
#pragma unroll
    for (int i = 0; i < 3; ++i) dst[i * 256 + tid] = src[i * 256 + tid];
  }
  __syncthreads();
  if (tid < 16) {
    float l = 0.f;
    for (int t = 0; t < 64; ++t) { l += cf[t * 48 + tid]; Lb[t * 16 + tid] = l; }
  }
  __syncthreads();
  {
    int t = tid >> 2, tp0 = (tid & 3) * 16;
    float4 cv[4], lv[4];
#pragma unroll
    for (int i = 0; i < 4; ++i) {
      cv[i] = *(const float4*)&cf[t * 48 + 32 + i * 4];
      lv[i] = *(const float4*)&Lb[t * 16 + i * 4];
    }
    float kv[16];
#pragma unroll
    for (int i = 0; i < 16; ++i) {
      int tp = tp0 + i;
      float k = 0.f;
      if (tp <= t) {
#pragma unroll
        for (int q = 0; q < 4; ++q) {
          float4 lpv = *(const float4*)&Lb[tp * 16 + q * 4];
          float4 fbv = *(const float4*)&cf[tp * 48 + 16 + q * 4];
          k += cv[q].x * __expf(lv[q].x - lpv.x) * fbv.x
             + cv[q].y * __expf(lv[q].y - lpv.y) * fbv.y
             + cv[q].z * __expf(lv[q].z - lpv.z) * fbv.z
             + cv[q].w * __expf(lv[q].w - lpv.w) * fbv.w;
        }
      }
      kv[i] = k;
    }
    bf16x8 lo, hi;
#pragma unroll
    for (int i = 0; i < 8; ++i) { lo[i] = (bf16_t)kv[i]; hi[i] = (bf16_t)kv[8 + i]; }
    unsigned b0 = (unsigned)(t * 128 + tp0 * 2) ^ ((unsigned)(t & 7) << 4);
    unsigned b1 = (unsigned)(t * 128 + tp0 * 2 + 16) ^ ((unsigned)(t & 7) << 4);
    *(bf16x8*)((char*)Km + b0) = lo;
    *(bf16x8*)((char*)Km + b1) = hi;
  }
  __syncthreads();
  int fr = lane & 15, kq = lane >> 4;
  int trow = (wave >> 1) * 32, wc = (wave & 1) * 64;
  f32x4 acc[2][4] = {};
#pragma unroll
  for (int kk = 0; kk < 2; ++kk) {
    int kb = kk * 4 + kq;
    bf16x8 af[2];
#pragma unroll
    for (int mi = 0; mi < 2; ++mi) {
      int row = trow + mi * 16 + fr;
      af[mi] = *(const bf16x8*)((const char*)Km +
                 ((unsigned)(row * 128 + kb * 16) ^ ((unsigned)(row & 7) << 4)));
    }
#pragma unroll
    for (int ni = 0; ni < 4; ++ni) {
      int ch = wc + ni * 16 + fr;
      bf16x8 bfr = *(const bf16x8*)((const char*)Ut +
                     ((unsigned)(ch * 128 + kb * 16) ^ ((unsigned)(ch & 7) << 4)));
#pragma unroll
      for (int mi = 0; mi < 2; ++mi)
        acc[mi][ni] = __builtin_amdgcn_mfma_f32_16x16x32_bf16(af[mi], bfr, acc[mi][ni], 0, 0, 0);
    }
  }
  {
    int s0 = kq * 8;
    bf16x8 cef[2];
    if (s0 < 16) {
#pragma unroll
      for (int mi = 0; mi < 2; ++mi) {
        int t = trow + mi * 16 + fr;
#pragma unroll
        for (int j = 0; j < 8; ++j)
          cef[mi][j] = (bf16_t)(cf[t * 48 + 32 + s0 + j] * __expf(Lb[t * 16 + s0 + j]));
      }
    } else {
#pragma unroll
      for (int mi = 0; mi < 2; ++mi)
#pragma unroll
        for (int j = 0; j < 8; ++j) cef[mi][j] = (bf16_t)0.f;
    }
#pragma unroll
    for (int ni = 0; ni < 4; ++ni) {
      int ch = wc + ni * 16 + fr;
      bf16x8 bhf = *(const bf16x8*)((const char*)Hb + ch * 64 + s0 * 2);
#pragma unroll
      for (int mi = 0; mi < 2; ++mi)
        acc[mi][ni] = __builtin_amdgcn_mfma_f32_16x16x32_bf16(cef[mi], bhf, acc[mi][ni], 0, 0, 0);
    }
  }
  {
    int64_t rowbase = (int64_t)b * 1024 + t0;
    int colbase = g * 128;
#pragma unroll
    for (int mi = 0; mi < 2; ++mi) {
#pragma unroll
      for (int ni = 0; ni < 4; ++ni) {
        int col = colbase + wc + ni * 16 + fr;
#pragma unroll
        for (int j = 0; j < 4; ++j) {
          int t = trow + mi * 16 + kq * 4 + j;
          float sg;
          if (GM) {
            sg = (float)gate_b[(rowbase + t) * 2048 + col];
          } else {
            float gv = gate_f[(rowbase + t) * (int64_t)gstride + col];
            sg = gv / (1.f + __expf(-gv));
          }
          yout[(rowbase + t) * 2048 + col] = (bf16_t)(acc[mi][ni][j] * sg);
        }
      }
    }
  }
}

// ======== epilogue helper (fallback gemm_bt only) ========
template <int EPI>
__device__ __forceinline__ void epi_store(float v, int64_t r, int64_t cn, int N,
                                          float* Cz, const float* bias,
                                          const float* res, bf16_t* obf,
                                          bf16_t* ogate, int z) {
  if (EPI & 1) v += bias[cn];
  if (EPI & 2) v += res[r * N + cn];
  if (EPI & 4) {
    float sv = v / (1.f + __expf(-v));
    if (cn < 2048) obf[r * 2048 + cn] = (bf16_t)sv;
    else ogate[r * 2048 + cn - 2048] = (bf16_t)sv;
  } else if (EPI & 8) {
    obf[r * N + cn] = (bf16_t)(v / (1.f + __expf(-v)));
  } else if (EPI & 16) {
    obf[(int64_t)z * ROWS * N + r * N + cn] = (bf16_t)v;
  } else {
    Cz[r * N + cn] = v;
  }
}

// bijective XCD swizzle over flattened grid (identity if nwg%8 != 0)
__device__ __forceinline__ void xcd_swz(int& bx, int& by, int& bz) {
  int gx = gridDim.x, gy = gridDim.y, gz = gridDim.z;
  int flat = blockIdx.x + gx * (blockIdx.y + gy * blockIdx.z);
  int nwg = gx * gy * gz;
  int swz = flat;
  if ((nwg & 7) == 0) swz = (flat & 7) * (nwg >> 3) + (flat >> 3);
  bx = swz % gx;
  int rem = swz / gx;
  by = rem % gy;
  bz = rem / gy;
}

// ---------------- bf16 GEMM 128x128, double-buffered 2-phase (fallback) -----
template <int EPI>
__global__ __launch_bounds__(256) void gemm_bt(const bf16_t* __restrict__ A,
                                               const bf16_t* __restrict__ Bw,
                                               float* __restrict__ C,
                                               const float* __restrict__ bias,
                                               const float* __restrict__ res,
                                               bf16_t* __restrict__ obf,
                                               bf16_t* __restrict__ ogate,
                                               int N, int Kps) {
  __shared__ bf16_t As[2][128 * 64];
  __shared__ bf16_t Bs[2][128 * 64];
  const int tid = threadIdx.x;
  const int wave = tid >> 6;
  const int lane = tid & 63;
  int bxi, byi, bzi;
  xcd_swz(bxi, byi, bzi);
  const int64_t m0 = (int64_t)byi * 128;
  const int64_t n0 = (int64_t)bxi * 128;
  const int K = Kps * gridDim.z;
  const int kbeg = bzi * Kps;
  float* Cz = C + (int64_t)bzi * ROWS * N;
  const int wm = (wave >> 1) * 64;
  const int wn = (wave & 1) * 64;
  f32x4 acc[4][4] = {};

  const int er = tid >> 3;
  const int ec = (tid * 8) & 63;
  const int fr = lane & 15;
  const int kq = (lane >> 4) * 8;

  auto stage = [&](int buf, int k0) {
#pragma unroll
    for (int i = 0; i < 4; ++i) {
      const bf16_t* ga = A + (m0 + er + i * 32) * K + k0 + ec;
      __builtin_amdgcn_global_load_lds((gvoid_t*)ga,
                                       (lvoid_t*)&As[buf][(i * 256 + wave * 64) * 8],
                                       16, 0, 0);
    }
#pragma unroll
    for (int i = 0; i < 4; ++i) {
      const bf16_t* gb = Bw + (n0 + er + i * 32) * K + k0 + ec;
      __builtin_amdgcn_global_load_lds((gvoid_t*)gb,
                                       (lvoid_t*)&Bs[buf][(i * 256 + wave * 64) * 8],
                                       16, 0, 0);
    }
  };
  auto compute = [&](int buf) {
#pragma unroll
    for (int kk = 0; kk < 2; ++kk) {
      bf16x8 af[4], bv[4];
#pragma unroll
      for (int mi = 0; mi < 4; ++mi)
        af[mi] = *reinterpret_cast<const bf16x8*>(&As[buf][(wm + mi * 16 + fr) * 64 + kk * 32 + kq]);
#pragma unroll
      for (int ni = 0; ni < 4; ++ni)
        bv[ni] = *reinterpret_cast<const bf16x8*>(&Bs[buf][(wn + ni * 16 + fr) * 64 + kk * 32 + kq]);
#pragma unroll
      for (int mi = 0; mi < 4; ++mi)
#pragma unroll
        for (int ni = 0; ni < 4; ++ni)
          acc[mi][ni] = __builtin_amdgcn_mfma_f32_16x16x32_bf16(af[mi], bv[ni], acc[mi][ni], 0, 0, 0);
    }
  };

  const int nk = Kps >> 6;  // assumed even
  stage(0, kbeg);
  asm volatile("s_waitcnt vmcnt(0)" ::: "memory");
  __builtin_amdgcn_s_barrier();
  int kc = kbeg;
  for (int t = 0; t < nk; t += 2) {
    stage(1, kc + 64);
    compute(0);
    asm volatile("s_waitcnt vmcnt(0)" ::: "memory");
    __builtin_amdgcn_s_barrier();
    if (t + 2 < nk) stage(0, kc + 128);
    compute(1);
    asm volatile("s_waitcnt vmcnt(0)" ::: "memory");
    __builtin_amdgcn_s_barrier();
    kc += 128;
  }

  const int crow = (lane >> 4) * 4;
  const int ccol = lane & 15;
#pragma unroll
  for (int mi = 0; mi < 4; ++mi)
#pragma unroll
    for (int ni = 0; ni < 4; ++ni)
#pragma unroll
      for (int j = 0; j < 4; ++j)
        epi_store<EPI>(acc[mi][ni][j], m0 + wm + mi * 16 + crow + j,
                       n0 + wn + ni * 16 + ccol, N, Cz, bias, res, obf, ogate,
                       bzi);
}

// ---------------- param GEMM (128x128, SK=4) + W_out/W_f1/W_f2 conversion ---
__global__ __launch_bounds__(256) void gemm_param_conv(
    const bf16_t* __restrict__ A, const bf16_t* __restrict__ Bw,
    bf16_t* __restrict__ pout,
    const float* __restrict__ W_out, const float* __restrict__ W_f1,
    const float* __restrict__ W_f2,
    bf16_t* o_out, bf16_t* o_f1, bf16_t* o_f2) {
  __shared__ bf16_t As[2][128 * 64];
  __shared__ bf16_t Bs[2][128 * 64];
  const int tid = threadIdx.x;
  if (blockIdx.x >= 320) {
    conv3(blockIdx.x - 320, tid, W_out, W_f1, W_f2, o_out, o_f1, o_f2);
    return;
  }
  const int flat = blockIdx.x;
  const int swz = (flat & 7) * 40 + (flat >> 3);  // 320 % 8 == 0, bijective
  const int bxi = swz % 5;
  const int byi = (swz / 5) % 16;
  const int bzi = swz / 80;
  const int wave = tid >> 6;
  const int lane = tid & 63;
  const int64_t m0 = (int64_t)byi * 128;
  const int64_t n0 = (int64_t)bxi * 128;
  const int K = 2048, Kps = 512;
  const int kbeg = bzi * Kps;
  const int wm = (wave >> 1) * 64;
  const int wn = (wave & 1) * 64;
  f32x4 acc[4][4] = {};
  const int er = tid >> 3;
  const int ec = (tid * 8) & 63;
  const int fr = lane & 15;
  const int kq = (lane >> 4) * 8;

  auto stage = [&](int buf, int k0) {
#pragma unroll
    for (int i = 0; i < 4; ++i) {
      const bf16_t* ga = A + (m0 + er + i * 32) * K + k0 + ec;
      __builtin_amdgcn_global_load_lds((gvoid_t*)ga,
                                       (lvoid_t*)&As[buf][(i * 256 + wave * 64) * 8],
                                       16, 0, 0);
    }
#pragma unroll
    for (int i = 0; i < 4; ++i) {
      const bf16_t* gb = Bw + (n0 + er + i * 32) * K + k0 + ec;
      __builtin_amdgcn_global_load_lds((gvoid_t*)gb,
                                       (lvoid_t*)&Bs[buf][(i * 256 + wave * 64) * 8],
                                       16, 0, 0);
    }
  };
  auto compute = [&](int buf) {
#pragma unroll
    for (int kk = 0; kk < 2; ++kk) {
      bf16x8 af[4], bv[4];
#pragma unroll
      for (int mi = 0; mi < 4; ++mi)
        af[mi] = *reinterpret_cast<const bf16x8*>(&As[buf][(wm + mi * 16 + fr) * 64 + kk * 32 + kq]);
#pragma unroll
      for (int ni = 0; ni < 4; ++ni)
        bv[ni] = *reinterpret_cast<const bf16x8*>(&Bs[buf][(wn + ni * 16 + fr) * 64 + kk * 32 + kq]);
#pragma unroll
      for (int mi = 0; mi < 4; ++mi)
#pragma unroll
        for (int ni = 0; ni < 4; ++ni)
          acc[mi][ni] = __builtin_amdgcn_mfma_f32_16x16x32_bf16(af[mi], bv[ni], acc[mi][ni], 0, 0, 0);
    }
  };

  const int nk = Kps >> 6;  // 8
  stage(0, kbeg);
  asm volatile("s_waitcnt vmcnt(0)" ::: "memory");
  __builtin_amdgcn_s_barrier();
  int kc = kbeg;
  for (int t = 0; t < nk; t += 2) {
    stage(1, kc + 64);
    compute(0);
    asm volatile("s_waitcnt vmcnt(0)" ::: "memory");
    __builtin_amdgcn_s_barrier();
    if (t + 2 < nk) stage(0, kc + 128);
    compute(1);
    asm volatile("s_waitcnt vmcnt(0)" ::: "memory");
    __builtin_amdgcn_s_barrier();
    kc += 128;
  }

  const int crow = (lane >> 4) * 4;
  const int ccol = lane & 15;
  bf16_t* pz = pout + (int64_t)bzi * ROWS * PPAD;
#pragma unroll
  for (int mi = 0; mi < 4; ++mi)
#pragma unroll
    for (int ni = 0; ni < 4; ++ni)
#pragma unroll
      for (int j = 0; j < 4; ++j) {
        int64_t r = m0 + wm + mi * 16 + crow + j;
        int64_t cn = n0 + wn + ni * 16 + ccol;
        pz[r * PPAD + cn] = (bf16_t)acc[mi][ni][j];
      }
}

// ---------------- bf16 GEMM 128x128, 8-wave, depth-2 counted pipeline -------
// 64KB LDS -> 2 blocks/CU (16 waves/CU): cross-block overlap hides drains.
// Per K-tile: reads Q0+Q1 -> lgkm(6) -> MFMA Q0 -> lgkm(0)+barrier ->
// restage buf (t+2) -> MFMA Q1 -> vmcnt(4)+barrier.
template <int EPI>
__global__ __launch_bounds__(512, 4) void gemm_big(const bf16_t* __restrict__ A,
                                                   const bf16_t* __restrict__ Bw,
                                                   float* __restrict__ C,
                                                   const float* __restrict__ bias,
                                                   const float* __restrict__ res,
                                                   bf16_t* __restrict__ obf,
                                                   bf16_t* __restrict__ ogate,
                                                   int N, int Kps) {
  __shared__ bf16_t As[2][128 * 64];
  __shared__ bf16_t Bs[2][128 * 64];
  const int tid = threadIdx.x;
  const int wave = tid >> 6;
  const int lane = tid & 63;
  int bxi, byi, bzi;
  xcd_swz(bxi, byi, bzi);
  const int64_t m0 = (int64_t)byi * 128;
  const int64_t n0 = (int64_t)bxi * 128;
  const int K = Kps * gridDim.z;
  const int kbeg = bzi * Kps;
  float* Cz = C + (int64_t)bzi * ROWS * N;
  (void)Cz; (void)res;
  const int wm = (wave >> 1) * 32;   // 4 M-wave rows of 32
  const int wc = (wave & 1) * 64;    // 2 N-wave cols of 64
  const int fr = lane & 15;
  const int kq16 = (lane >> 4) * 16;
  const int er = tid >> 3;                              // staging row 0..63
  const int ec_sw = ((tid & 7) * 8) ^ ((er & 7) << 3);  // swizzled src col
  f32x4 acc[2][4] = {};

  auto stage = [&](int buf, int k0) {
#pragma unroll
    for (int i = 0; i < 2; ++i) {
      const bf16_t* ga = A + (m0 + er + i * 64) * K + k0 + ec_sw;
      __builtin_amdgcn_global_load_lds((gvoid_t*)ga,
          (lvoid_t*)((char*)&As[buf][0] + i * 8192 + wave * 1024), 16, 0, 0);
    }
#pragma unroll
    for (int i = 0; i < 2; ++i) {
      const bf16_t* gb = Bw + (n0 + er + i * 64) * K + k0 + ec_sw;
      __builtin_amdgcn_global_load_lds((gvoid_t*)gb,
          (lvoid_t*)((char*)&Bs[buf][0] + i * 8192 + wave * 1024), 16, 0, 0);
    }
  };

  const int nk = Kps >> 6;
  stage(0, kbeg);
  if (nk > 1) {
    stage(1, kbeg + 64);
    asm volatile("s_waitcnt vmcnt(4)" ::: "memory");
  } else {
    asm volatile("s_waitcnt vmcnt(0)" ::: "memory");
  }
  __builtin_amdgcn_s_barrier();
  __builtin_amdgcn_sched_barrier(0);

  for (int t = 0; t < nk; ++t) {
    const int buf = t & 1;
    bf16x8 af[2][2], bf[2][4];
#pragma unroll
    for (int kk = 0; kk < 2; ++kk) {
#pragma unroll
      for (int mi = 0; mi < 2; ++mi) {
        int r = wm + mi * 16 + fr;
        af[kk][mi] = *(const bf16x8*)((const char*)&As[buf][0] + r * 128 +
                       ((kk * 64 + kq16) ^ ((r & 7) << 4)));
      }
#pragma unroll
      for (int ni = 0; ni < 4; ++ni) {
        int r = wc + ni * 16 + fr;
        bf[kk][ni] = *(const bf16x8*)((const char*)&Bs[buf][0] + r * 128 +
                       ((kk * 64 + kq16) ^ ((r & 7) << 4)));
      }
    }
    asm volatile("s_waitcnt lgkmcnt(6)" ::: "memory");
    __builtin_amdgcn_sched_barrier(0);
    __builtin_amdgcn_s_setprio(1);
#pragma unroll
    for (int mi = 0; mi < 2; ++mi)
#pragma unroll
      for (int ni = 0; ni < 4; ++ni)
        acc[mi][ni] = __builtin_amdgcn_mfma_f32_16x16x32_bf16(
            af[0][mi], bf[0][ni], acc[mi][ni], 0, 0, 0);
    __builtin_amdgcn_s_setprio(0);
    __builtin_amdgcn_sched_barrier(0);
    asm volatile("s_waitcnt lgkmcnt(0)" ::: "memory");
    __builtin_amdgcn_sched_barrier(0);
    __builtin_amdgcn_s_barrier();          // all waves done reading buf
    __builtin_amdgcn_sched_barrier(0);
    if (t + 2 < nk) stage(buf, kbeg + (t + 2) * 64);  // overwrite buf, 2 ahead
    __builtin_amdgcn_s_setprio(1);
#pragma unroll
    for (int mi = 0; mi < 2; ++mi)
#pragma unroll
      for (int ni = 0; ni < 4; ++ni)
        acc[mi][ni] = __builtin_amdgcn_mfma_f32_16x16x32_bf16(
            af[1][mi], bf[1][ni], acc[mi][ni], 0, 0, 0);
    __builtin_amdgcn_s_setprio(0);
    if (t + 1 < nk) {
      if (t + 2 < nk) asm volatile("s_waitcnt vmcnt(4)" ::: "memory");
      else            asm volatile("s_waitcnt vmcnt(0)" ::: "memory");
      __builtin_amdgcn_s_barrier();        // stage(t+1) landed
      __builtin_amdgcn_sched_barrier(0);
    }
  }

  // ---- coalesced epilogue: per-wave 32x64 bf16 tile in dead Bs, XOR-swizzled
  __syncthreads();
  {
    char* ep = (char*)&Bs[0][0] + wave * 4096;  // 32 rows x 128B
    const int crow = (lane >> 4) * 4;
    const int ccol = lane & 15;
#pragma unroll
    for (int mi = 0; mi < 2; ++mi) {
#pragma unroll
      for (int ni = 0; ni < 4; ++ni) {
        int lc = ni * 16 + ccol;
        float bv = (EPI & 1) ? bias[n0 + wc + lc] : 0.f;
#pragma unroll
        for (int j = 0; j < 4; ++j) {
          int lr = mi * 16 + crow + j;
          float v = acc[mi][ni][j] + bv;
          if (EPI & 12) v = v / (1.f + __expf(-v));
          *(bf16_t*)(ep + lr * 128 + ((lc * 2) ^ ((lr & 7) << 4))) = (bf16_t)v;
        }
      }
    }
    // read back row-major, 16B per lane; 8 consecutive lanes = one 128B row
#pragma unroll
    for (int i = 0; i < 4; ++i) {
      int idx = i * 64 + lane;
      int row = idx >> 3;
      int grp = idx & 7;
      bf16x8 v = *(const bf16x8*)(ep + row * 128 + ((grp * 16) ^ ((row & 7) << 4)));
      int64_t r = m0 + wm + row;
      int64_t cn = n0 + wc + grp * 8;
      bf16_t* dst;
      if (EPI & 4) {
        dst = (cn < 2048) ? (obf + r * 2048 + cn) : (ogate + r * 2048 + cn - 2048);
      } else if (EPI & 16) {
        dst = obf + (int64_t)bzi * ROWS * N + r * N + cn;
      } else {
        dst = obf + r * N + cn;
      }
      *(bf16x8*)dst = v;
    }
  }
}

extern "C" void kernel_launch(void* const* d_in, const int* in_sizes, int n_in,
                              void* d_out, int out_size, void* d_ws, size_t ws_size,
                              hipStream_t stream) {
  const float* x       = (const float*)d_in[0];
  const float* A_log   = (const float*)d_in[1];
  const float* g1      = (const float*)d_in[2];
  const float* g2      = (const float*)d_in[3];
  const float* W_in    = (const float*)d_in[4];
  const float* W_param = (const float*)d_in[5];
  const float* W_out   = (const float*)d_in[6];
  const float* W_ffn1  = (const float*)d_in[7];
  const float* b_ffn1  = (const float*)d_in[8];
  const float* W_ffn2  = (const float*)d_in[9];
  const float* b_ffn2  = (const float*)d_in[10];
  float* out = (float*)d_out;

  char* ws = (char*)d_ws;
  size_t off = 0;
  auto alloc = [&](size_t bytes) {
    char* p = ws + off;
    off += (bytes + 255) & ~(size_t)255;
    return p;
  };
  bf16_t* wb_in  = (bf16_t*)alloc(4096ull * 1024 * 2);
  bf16_t* wb_par = (bf16_t*)alloc((size_t)PPAD * 2048 * 2);
  bf16_t* wb_out = (bf16_t*)alloc(1024ull * 2048 * 2);
  bf16_t* wb_f1  = (bf16_t*)alloc(4096ull * 1024 * 2);
  bf16_t* wb_f2  = (bf16_t*)alloc(1024ull * 4096 * 2);
  bf16_t* zbuf   = (bf16_t*)alloc(2048ull * 1024 * 2);   // z, later h2
  float*  xzg    = (float*)alloc(2048ull * 4096 * 4);    // sgate bf16 (sk) / fp32 (fallback)
  float*  params = (float*)alloc(2048ull * PPAD * 4);    // fallback GEMM out; S/Etot overlay
  float*  ssmp   = (float*)alloc(32ull * 1024 * 48 * 4); // fallback only
  float*  xmid   = (float*)alloc(2048ull * 1024 * 4);    // bf16 (sk) / fp32 (fallback)
  char*   regA   = alloc(2048ull * 4096 * 2);            // 16MB union
  bf16_t* xz_act = (bf16_t*)regA;
  bf16_t* y_b16  = (bf16_t*)(regA + 2048ull * 2048 * 2);
  bf16_t* f_act  = (bf16_t*)regA;
  bf16_t* sgate  = (bf16_t*)xzg;                         // [2048][2048] bf16 (sk)
  bf16_t* xmid_b = (bf16_t*)xmid;                        // bf16 residual (sk)
  float* Sbuf = params;
  float* Etot = params + 32ull * 16 * 16 * 128;
  float*  psum = (float*)alloc(4ull * ROWS * 1024 * 4);  // fp32 partials (fallback)
  bf16_t* pb16 = (bf16_t*)psum;                          // bf16 partials overlay
  const bool sk = (off <= ws_size);

  dim3 b256(256), b512(512);
  // W_in/W_param -> bf16 + z = rmsnorm(x,g1)
  prep0<<<7424, b256, 0, stream>>>(W_in, W_param, wb_in, wb_par, x, g1, zbuf);

  if (sk) {
    // xz|gate = z @ W_in^T, fused: silu(xz)->xz_act, silu(gate)->sgate (bf16)
    gemm_big<4><<<dim3(32, 16), b512, 0, stream>>>(zbuf, wb_in, psum, nullptr, nullptr, xz_act, sgate, 4096, 1024);
    // param partials (bf16, SK=4) + W_out/W_f1/W_f2 conversion riding along
    gemm_param_conv<<<10560, b256, 0, stream>>>(xz_act, wb_par, pb16,
                                                W_out, W_ffn1, W_ffn2,
                                                wb_out, wb_f1, wb_f2);
    // chunked scan (coefficient prep inlined; combine inlined in ssm_out)
    ssm_chunk<1><<<480, b256, 0, stream>>>(nullptr, pb16, A_log, xz_act, Sbuf, Etot);
    ssm_out<1, 1><<<512, b256, 0, stream>>>(nullptr, pb16, A_log, xz_act, Sbuf, Etot, nullptr, sgate, 2048, y_b16);
    // xmid = x + y @ W_out^T (SK=4, bf16 partials) fused reduce+rmsnorm
    gemm_big<16><<<dim3(8, 16, 4), b512, 0, stream>>>(y_b16, wb_out, psum, nullptr, nullptr, pb16, nullptr, 1024, 512);
    reduce_rms<<<2048, b256, 0, stream>>>(pb16, x, g2, xmid_b, zbuf);
    // ffn1 + bias + silu -> f_act bf16 (fused)
    gemm_big<9><<<dim3(32, 16), b512, 0, stream>>>(zbuf, wb_f1, psum, b_ffn1, nullptr, f_act, nullptr, 4096, 1024);
    // out = xmid + b_ffn2 + f_act @ W_ffn2^T (SK=4, bf16 partials)
    gemm_big<16><<<dim3(8, 16, 4), b512, 0, stream>>>(f_act, wb_f2, psum, nullptr, nullptr, pb16, nullptr, 1024, 1024);
    reduce_bias<<<2048, b256, 0, stream>>>(pb16, xmid_b, b_ffn2, out);
  } else {
    cvt3_k<<<10240, b256, 0, stream>>>(W_out, W_ffn1, W_ffn2, wb_out, wb_f1, wb_f2);
    gemm_bt<0><<<dim3(32, 16), b256, 0, stream>>>(zbuf, wb_in, xzg, nullptr, nullptr, nullptr, nullptr, 4096, 1024);
    silu_cvt<<<4096, b256, 0, stream>>>(xzg, xz_act, 4096, 2048);
    gemm_bt<0><<<dim3(PPAD / 128, 16), b256, 0, stream>>>(xz_act, wb_par, params, nullptr, nullptr, nullptr, nullptr, PPAD, 2048);
    ssm_prep<<<128, b256, 0, stream>>>(params, A_log, ssmp);
    ssm_chunk<0><<<480, b256, 0, stream>>>(ssmp, nullptr, A_log, xz_act, Sbuf, Etot);
    ssm_out<0, 0><<<512, b256, 0, stream>>>(ssmp, nullptr, A_log, xz_act, Sbuf, Etot, xzg + 2048, nullptr, 4096, y_b16);
    gemm_bt<2><<<dim3(8, 16), b256, 0, stream>>>(y_b16, wb_out, xmid, nullptr, x, nullptr, nullptr, 1024, 2048);
    rmsnorm_k<<<2048, b256, 0, stream>>>(xmid, g2, zbuf);
    gemm_bt<1><<<dim3(32, 16), b256, 0, stream>>>(zbuf, wb_f1, xzg, b_ffn1, nullptr, nullptr, nullptr, 4096, 1024);
    silu_cvt<<<8192, b256, 0, stream>>>(xzg, f_act, 4096, 4096);
    gemm_bt<3><<<dim3(8, 16), b256, 0, stream>>>(f_act, wb_f2, out, b_ffn2, xmid, nullptr, nullptr, 1024, 4096);
  }
}